// Round 2
// baseline (1791.193 us; speedup 1.0000x reference)
//
#include <hip/hip_runtime.h>
#include <hip/hip_fp16.h>
#include <math.h>

#define TT   512
#define BB   512
#define DIN  64
#define DLAT 128
#define KK   192                  // DLAT + DIN
#define NCH  24                   // KK / 8
#define WPACK_HALVES (3 * NCH * DLAT * 8)   // 73728 f16 = 147456 B
// dynamic LDS: weights + h_s[2][128] + hr_s[2][128] + x_s[2][2][64]
#define SMEM_BYTES (WPACK_HALVES * 2 + 256 * 4 + 256 * 4 + 256 * 4)

typedef _Float16 half8 __attribute__((ext_vector_type(8)));

__device__ __forceinline__ float sigmoidf_(float x) { return 1.f / (1.f + __expf(-x)); }
__device__ __forceinline__ float tanhf_(float x)    { return 1.f - 2.f / (__expf(2.f * x) + 1.f); }

// Pack W[g][j][k] (f32 row-major [DLAT][KK]) into chunk-major f16:
// wp[(((g*NCH + c)*DLAT + j)*8 + e] = W[g][j][c*8+e]
__global__ void pack_w(const float* __restrict__ Wz, const float* __restrict__ Wr,
                       const float* __restrict__ Wi, _Float16* __restrict__ wp) {
    int i = blockIdx.x * 256 + threadIdx.x;
    if (i >= WPACK_HALVES) return;
    int e  = i & 7;
    int slot = i >> 3;
    int j  = slot & (DLAT - 1);
    int gc = slot >> 7;              // g*NCH + c
    int c  = gc % NCH;
    int g  = gc / NCH;
    const float* W = (g == 0) ? Wz : ((g == 1) ? Wr : Wi);
    wp[i] = (_Float16)W[j * KK + c * 8 + e];
}

__device__ __forceinline__ void dot8(float& acc0, float& acc1,
                                     const float4 m0, const float4 m1,
                                     const half8 wv) {
    acc0 = fmaf(m0.x, (float)wv[0], acc0);
    acc1 = fmaf(m0.y, (float)wv[1], acc1);
    acc0 = fmaf(m0.z, (float)wv[2], acc0);
    acc1 = fmaf(m0.w, (float)wv[3], acc1);
    acc0 = fmaf(m1.x, (float)wv[4], acc0);
    acc1 = fmaf(m1.y, (float)wv[5], acc1);
    acc0 = fmaf(m1.z, (float)wv[6], acc0);
    acc1 = fmaf(m1.w, (float)wv[7], acc1);
}

// Persistent recurrent kernel: block handles 2 batch rows for all T steps.
// thread = (bl = tid>>7 in [0,2), j = tid&127). No inter-block deps.
__global__ __launch_bounds__(256, 1) void gru_rec(
    const float* __restrict__ seqs, const float* __restrict__ h0,
    const float* __restrict__ bz, const float* __restrict__ br,
    const float* __restrict__ bi, const _Float16* __restrict__ wp,
    float* __restrict__ out)
{
    extern __shared__ char smem[];
    half8* __restrict__ wlds = (half8*)smem;                 // 9216 chunk-slots
    float* h_s  = (float*)(smem + WPACK_HALVES * 2);         // [2][DLAT]
    float* hr_s = h_s + 256;                                 // [2][DLAT]
    float* x_s  = hr_s + 256;                                // [2][2][DIN] double buffer

    const int tid = threadIdx.x;
    const int j   = tid & (DLAT - 1);
    const int bl  = tid >> 7;
    const int b0  = (int)blockIdx.x * 2;
    const int bg  = b0 + bl;

    // Stage weights into LDS (coalesced 16B chunks).
    for (int i = tid; i < WPACK_HALVES / 8; i += 256)
        wlds[i] = ((const half8*)wp)[i];

    // Initial hidden state; out[0] = h0.
    float hv = h0[bg * DLAT + j];
    h_s[tid] = hv;
    out[bg * DLAT + j] = hv;

    const float bzj = bz[j], brj = br[j], bij = bi[j];

    // Preload x[0] into buffer 0.
    if (tid < 2 * DIN) {
        int bl2 = tid >> 6, k = tid & 63;
        x_s[bl2 * DIN + k] = seqs[(0 * BB + b0 + bl2) * DIN + k];
    }
    __syncthreads();

    for (int t = 0; t < TT; ++t) {
        const int p = t & 1;
        const float* __restrict__ hcur = h_s + bl * DLAT;
        const float* __restrict__ xcur = x_s + p * DLAT + bl * DIN;

        // ---- phase 1: z and r gates ----
        float az0 = bzj, az1 = 0.f, ar0 = brj, ar1 = 0.f;
        #pragma unroll
        for (int c = 0; c < NCH; ++c) {
            float4 m0, m1;
            if (c < 16) {                       // h part of merge
                m0 = ((const float4*)hcur)[2 * c];
                m1 = ((const float4*)hcur)[2 * c + 1];
            } else {                            // x part of merge
                m0 = ((const float4*)xcur)[2 * (c - 16)];
                m1 = ((const float4*)xcur)[2 * (c - 16) + 1];
            }
            half8 wz_ = wlds[(0 * NCH + c) * DLAT + j];
            half8 wr_ = wlds[(1 * NCH + c) * DLAT + j];
            dot8(az0, az1, m0, m1, wz_);
            dot8(ar0, ar1, m0, m1, wr_);
        }
        float z = sigmoidf_(az0 + az1);
        float r = sigmoidf_(ar0 + ar1);
        float hold = hcur[j];
        hr_s[tid] = hold * r;

        // Prefetch next x into the other buffer (no reader of p^1 in flight).
        if (t + 1 < TT && tid < 2 * DIN) {
            int bl2 = tid >> 6, k = tid & 63;
            x_s[(p ^ 1) * DLAT + bl2 * DIN + k] =
                seqs[((t + 1) * BB + b0 + bl2) * DIN + k];
        }
        __syncthreads();   // hr ready; everyone done reading h_s

        // ---- phase 2: candidate ----
        const float* __restrict__ hrcur = hr_s + bl * DLAT;
        float ai0 = bij, ai1 = 0.f;
        #pragma unroll
        for (int c = 0; c < NCH; ++c) {
            float4 m0, m1;
            if (c < 16) {                       // (h*r) part
                m0 = ((const float4*)hrcur)[2 * c];
                m1 = ((const float4*)hrcur)[2 * c + 1];
            } else {                            // x part
                m0 = ((const float4*)xcur)[2 * (c - 16)];
                m1 = ((const float4*)xcur)[2 * (c - 16) + 1];
            }
            half8 wi_ = wlds[(2 * NCH + c) * DLAT + j];
            dot8(ai0, ai1, m0, m1, wi_);
        }
        float cand = tanhf_(ai0 + ai1);
        float hn = fmaf(z, cand - hold, hold);   // (1-z)*h + z*cand
        h_s[tid] = hn;
        out[((t + 1) * BB + bg) * DLAT + j] = hn;
        __syncthreads();   // h_s update visible before next step
    }
}

extern "C" void kernel_launch(void* const* d_in, const int* in_sizes, int n_in,
                              void* d_out, int out_size, void* d_ws, size_t ws_size,
                              hipStream_t stream) {
    const float* seqs = (const float*)d_in[0];
    const float* h0   = (const float*)d_in[1];
    const float* Wz   = (const float*)d_in[2];
    const float* bz   = (const float*)d_in[3];
    const float* Wr   = (const float*)d_in[4];
    const float* br   = (const float*)d_in[5];
    const float* Wi   = (const float*)d_in[6];
    const float* bi   = (const float*)d_in[7];
    float* out = (float*)d_out;
    _Float16* wp = (_Float16*)d_ws;

    // Allow >64KB dynamic LDS (idempotent; not a stream op, capture-safe).
    (void)hipFuncSetAttribute((const void*)gru_rec,
                              hipFuncAttributeMaxDynamicSharedMemorySize, SMEM_BYTES);

    pack_w<<<(WPACK_HALVES + 255) / 256, 256, 0, stream>>>(Wz, Wr, Wi, wp);
    gru_rec<<<BB / 2, 256, SMEM_BYTES, stream>>>(seqs, h0, bz, br, bi, wp, out);
}

// Round 3
// 868.302 us; speedup vs baseline: 2.0629x; 2.0629x over previous
//
#include <hip/hip_runtime.h>
#include <math.h>

#define TT   512
#define BB   512
#define DIN  64
#define DLAT 128
#define KKK  192                 // DLAT + DIN

typedef _Float16 half8 __attribute__((ext_vector_type(8)));
typedef _Float16 half4 __attribute__((ext_vector_type(4)));
typedef float    f32x4 __attribute__((ext_vector_type(4)));

#define MFMA16(A, B, C) __builtin_amdgcn_mfma_f32_16x16x32_f16((A), (B), (C), 0, 0, 0)

__device__ __forceinline__ float sigmoidf_(float x) { return 1.f / (1.f + __expf(-x)); }
__device__ __forceinline__ float tanhf_(float x)    { return 1.f - 2.f / (__expf(2.f * x) + 1.f); }

// Persistent GRU: 32 blocks x 256 threads (4 waves). Block owns 16 batch rows.
// Wave w owns output cols [32w, 32w+32) (2 n-tiles) for z, r (phase 1) and cand
// (phase 2). Weights are register-resident MFMA B-fragments (f16). h state is
// register-resident (C-layout slots coincide across steps). LDS holds only the
// f16 A-operands: h (16x128), h*r (16x128), x double-buffered (2x16x64), all
// row-padded +8 f16 (stride 272B == 4 mod 32 banks -> conflict-free frags).
__global__ __launch_bounds__(256, 1) void gru_mfma(
    const float* __restrict__ seqs, const float* __restrict__ h0,
    const float* __restrict__ bz, const float* __restrict__ br,
    const float* __restrict__ bi,
    const float* __restrict__ Wz, const float* __restrict__ Wr,
    const float* __restrict__ Wi, float* __restrict__ out)
{
    __shared__ __align__(16) _Float16 hA [16][136];
    __shared__ __align__(16) _Float16 hrA[16][136];
    __shared__ __align__(16) _Float16 xb [2][16][72];

    const int tid = threadIdx.x;
    const int w   = tid >> 6;          // wave 0..3
    const int l   = tid & 63;
    const int q   = l >> 4;            // A/B frag k-group
    const int ln  = l & 15;            // frag row/col index
    const int b0  = (int)blockIdx.x * 16;

    // ---- weight fragments -> registers (one-time) ----
    // B-frag for n-tile base n0, k-tile kt: lane holds W[n0+ln][kt*32+q*8 .. +8]
    half8 wz[2][6], wr[2][6], wi[2][6];
    #pragma unroll
    for (int s = 0; s < 2; ++s) {
        const int n = 32 * w + 16 * s + ln;
        #pragma unroll
        for (int kt = 0; kt < 6; ++kt) {
            const int k0 = kt * 32 + q * 8;
            const float4 v0 = *(const float4*)&Wz[n * KKK + k0];
            const float4 v1 = *(const float4*)&Wz[n * KKK + k0 + 4];
            wz[s][kt] = (half8){(_Float16)v0.x, (_Float16)v0.y, (_Float16)v0.z, (_Float16)v0.w,
                                (_Float16)v1.x, (_Float16)v1.y, (_Float16)v1.z, (_Float16)v1.w};
            const float4 r0 = *(const float4*)&Wr[n * KKK + k0];
            const float4 r1 = *(const float4*)&Wr[n * KKK + k0 + 4];
            wr[s][kt] = (half8){(_Float16)r0.x, (_Float16)r0.y, (_Float16)r0.z, (_Float16)r0.w,
                                (_Float16)r1.x, (_Float16)r1.y, (_Float16)r1.z, (_Float16)r1.w};
            const float4 i0 = *(const float4*)&Wi[n * KKK + k0];
            const float4 i1 = *(const float4*)&Wi[n * KKK + k0 + 4];
            wi[s][kt] = (half8){(_Float16)i0.x, (_Float16)i0.y, (_Float16)i0.z, (_Float16)i0.w,
                                (_Float16)i1.x, (_Float16)i1.y, (_Float16)i1.z, (_Float16)i1.w};
        }
    }
    float bzv[2], brv[2], biv[2];
    #pragma unroll
    for (int s = 0; s < 2; ++s) {
        const int n = 32 * w + 16 * s + ln;
        bzv[s] = bz[n]; brv[s] = br[n]; biv[s] = bi[n];
    }

    // ---- h state in registers (C-layout slots), out[0], hA init ----
    float h[2][4];
    #pragma unroll
    for (int s = 0; s < 2; ++s)
        #pragma unroll
        for (int i = 0; i < 4; ++i)
            h[s][i] = h0[(size_t)(b0 + 4 * q + i) * DLAT + 32 * w + 16 * s + ln];

    for (int idx = tid; idx < 16 * DLAT; idx += 256) {
        const int m = idx >> 7, c = idx & 127;
        const float v = h0[(size_t)(b0 + m) * DLAT + c];
        out[(size_t)(b0 + m) * DLAT + c] = v;
        hA[m][c] = (_Float16)v;
    }
    // x[0]
    {
        const int m = tid >> 4, k4 = tid & 15;
        const float4 xv = *(const float4*)&seqs[((size_t)0 * BB + b0 + m) * DIN + k4 * 4];
        *(half4*)&xb[0][m][k4 * 4] =
            (half4){(_Float16)xv.x, (_Float16)xv.y, (_Float16)xv.z, (_Float16)xv.w};
    }
    __syncthreads();

    for (int t = 0; t < TT; ++t) {
        const int p = t & 1;

        // prefetch x[t+1] (latency hidden under phase-1 MFMAs)
        float4 xv;
        const int xm = tid >> 4, xk = tid & 15;
        if (t + 1 < TT)
            xv = *(const float4*)&seqs[((size_t)(t + 1) * BB + b0 + xm) * DIN + xk * 4];

        // A fragments: kt 0..3 from h, kt 4..5 from x (reused in phase 2)
        half8 a[6];
        #pragma unroll
        for (int kt = 0; kt < 4; ++kt)
            a[kt] = *(const half8*)&hA[ln][kt * 32 + q * 8];
        #pragma unroll
        for (int kt = 0; kt < 2; ++kt)
            a[4 + kt] = *(const half8*)&xb[p][ln][kt * 32 + q * 8];

        // ---- phase 1: z, r ----
        f32x4 az[2] = {{0.f, 0.f, 0.f, 0.f}, {0.f, 0.f, 0.f, 0.f}};
        f32x4 ar[2] = {{0.f, 0.f, 0.f, 0.f}, {0.f, 0.f, 0.f, 0.f}};
        #pragma unroll
        for (int s = 0; s < 2; ++s)
            #pragma unroll
            for (int kt = 0; kt < 6; ++kt) {
                az[s] = MFMA16(a[kt], wz[s][kt], az[s]);
                ar[s] = MFMA16(a[kt], wr[s][kt], ar[s]);
            }

        float zz[2][4];
        #pragma unroll
        for (int s = 0; s < 2; ++s)
            #pragma unroll
            for (int i = 0; i < 4; ++i) {
                const float zv = sigmoidf_(az[s][i] + bzv[s]);
                const float rv = sigmoidf_(ar[s][i] + brv[s]);
                zz[s][i] = zv;
                hrA[4 * q + i][32 * w + 16 * s + ln] = (_Float16)(h[s][i] * rv);
            }

        // stage x[t+1] into the idle buffer (its last reader was step t-1)
        if (t + 1 < TT)
            *(half4*)&xb[p ^ 1][xm][xk * 4] =
                (half4){(_Float16)xv.x, (_Float16)xv.y, (_Float16)xv.z, (_Float16)xv.w};

        __syncthreads();   // hr visible; x staged

        // ---- phase 2: candidate ----
        half8 a2[4];
        #pragma unroll
        for (int kt = 0; kt < 4; ++kt)
            a2[kt] = *(const half8*)&hrA[ln][kt * 32 + q * 8];

        f32x4 ai[2] = {{0.f, 0.f, 0.f, 0.f}, {0.f, 0.f, 0.f, 0.f}};
        #pragma unroll
        for (int s = 0; s < 2; ++s) {
            #pragma unroll
            for (int kt = 0; kt < 4; ++kt)
                ai[s] = MFMA16(a2[kt], wi[s][kt], ai[s]);
            #pragma unroll
            for (int kt = 4; kt < 6; ++kt)
                ai[s] = MFMA16(a[kt], wi[s][kt], ai[s]);
        }

        #pragma unroll
        for (int s = 0; s < 2; ++s)
            #pragma unroll
            for (int i = 0; i < 4; ++i) {
                const float cand = tanhf_(ai[s][i] + biv[s]);
                const float hn = h[s][i] + zz[s][i] * (cand - h[s][i]);
                h[s][i] = hn;
                const int m = 4 * q + i, c = 32 * w + 16 * s + ln;
                hA[m][c] = (_Float16)hn;
                out[((size_t)(t + 1) * BB + b0 + m) * DLAT + c] = hn;
            }

        __syncthreads();   // new h visible for next step's fragments
    }
}

extern "C" void kernel_launch(void* const* d_in, const int* in_sizes, int n_in,
                              void* d_out, int out_size, void* d_ws, size_t ws_size,
                              hipStream_t stream) {
    const float* seqs = (const float*)d_in[0];
    const float* h0   = (const float*)d_in[1];
    const float* Wz   = (const float*)d_in[2];
    const float* bz   = (const float*)d_in[3];
    const float* Wr   = (const float*)d_in[4];
    const float* br   = (const float*)d_in[5];
    const float* Wi   = (const float*)d_in[6];
    const float* bi   = (const float*)d_in[7];
    float* out = (float*)d_out;

    gru_mfma<<<BB / 16, 256, 0, stream>>>(seqs, h0, bz, br, bi, Wz, Wr, Wi, out);
}